// Round 15
// baseline (276.674 us; speedup 1.0000x reference)
//
#include <hip/hip_runtime.h>
#include <hip/hip_bf16.h>
#include <stdint.h>

// B=4, C=512, H=W=64 -> N=4096. Channel-first x [B,C,N].
#define C_DIM 512
#define N_DIM 4096
#define B_DIM 4

typedef __bf16 bf16x8 __attribute__((ext_vector_type(8)));
typedef float f32x4 __attribute__((ext_vector_type(4)));
typedef int i32x8 __attribute__((ext_vector_type(8)));
#define AS1 __attribute__((address_space(1)))
#define AS3 __attribute__((address_space(3)))

static __device__ __forceinline__ unsigned short f2bf(float x) {
  unsigned u = __float_as_uint(x);
  unsigned r = (u + 0x7fffu + ((u >> 16) & 1u)) >> 16;
  return (unsigned short)r;
}
static __device__ __forceinline__ unsigned char f2fp8(float x) {
  return (unsigned char)__builtin_amdgcn_cvt_pk_fp8_f32(x, x, 0, false);
}

// weights -> bf16: Wq, Wk, Wp straight; Wv transposed (z==2) for Wpv GEMM.
__global__ __launch_bounds__(256) void cvtT_weights(
    const float* __restrict__ wq, const float* __restrict__ wk,
    const float* __restrict__ wv, const float* __restrict__ wp,
    unsigned short* __restrict__ oq, unsigned short* __restrict__ ok,
    unsigned short* __restrict__ ovt, unsigned short* __restrict__ op) {
  __shared__ float t[32][33];
  const int zz = blockIdx.z;
  const float* w = zz == 0 ? wq : zz == 1 ? wk : zz == 2 ? wv : wp;
  unsigned short* o = zz == 0 ? oq : zz == 1 ? ok : zz == 2 ? ovt : op;
  const int r0 = blockIdx.y * 32, c0 = blockIdx.x * 32;
  const int tx = threadIdx.x, ty = threadIdx.y;
  if (zz == 2) {
    #pragma unroll
    for (int i = ty; i < 32; i += 8) t[i][tx] = w[(r0 + i) * C_DIM + c0 + tx];
    __syncthreads();
    #pragma unroll
    for (int i = ty; i < 32; i += 8)
      o[(size_t)(c0 + i) * C_DIM + r0 + tx] = f2bf(t[tx][i]);
  } else {
    #pragma unroll
    for (int i = ty; i < 32; i += 8)
      o[(size_t)(r0 + i) * C_DIM + c0 + tx] = f2bf(w[(r0 + i) * C_DIM + c0 + tx]);
  }
}

// bvp[o] = sum_m wp[o,m]*bv[m]  (1 block, 512 thr, f32 exact)
__global__ __launch_bounds__(512) void vec_bvp(
    const float* __restrict__ wp, const float* __restrict__ bv,
    float* __restrict__ bvp) {
  const int t = threadIdx.x;
  float s = 0.f;
  #pragma unroll 8
  for (int m = 0; m < C_DIM; ++m) s += wp[(size_t)t * C_DIM + m] * bv[m];
  bvp[t] = s;
}

// x [B,C,N] f32 -> Xt [B,N,C] bf16
__global__ __launch_bounds__(256) void transpose_x(
    const float* __restrict__ x, unsigned short* __restrict__ Xt) {
  __shared__ float t[32][33];
  const int b = blockIdx.z;
  const float* xb = x + (size_t)b * C_DIM * N_DIM;
  unsigned short* xtb = Xt + (size_t)b * N_DIM * C_DIM;
  const int n0 = blockIdx.x * 32, c0 = blockIdx.y * 32;
  const int tx = threadIdx.x, ty = threadIdx.y;
  #pragma unroll
  for (int i = ty; i < 32; i += 8)
    t[i][tx] = xb[(size_t)(c0 + i) * N_DIM + n0 + tx];
  __syncthreads();
  #pragma unroll
  for (int i = ty; i < 32; i += 8)
    xtb[(size_t)(n0 + i) * C_DIM + c0 + tx] = f2bf(t[tx][i]);
}

__global__ __launch_bounds__(256) void zero_buf(float* __restrict__ p, int n) {
  int i = blockIdx.x * 256 + threadIdx.x;
  if (i < n) p[i] = 0.f;
}

// ---------------- 128^2-tile 2-phase NT GEMM body (bf16 inputs) ------------
// BIAS: 0 none, 1 +bias[col], 2 +bias[row]. OUT8: fp8 vs bf16 output.
template<int BIAS, int OUT8>
__device__ __forceinline__ void gemm128_body(
    unsigned short* As, unsigned short* Bs,
    const unsigned short* __restrict__ A, const unsigned short* __restrict__ B,
    void* __restrict__ Cv, int K, int ldc,
    const float* __restrict__ bias, int bx, int by) {
  const int tid = threadIdx.x;
  const int wid = tid >> 6, lane = tid & 63;
  const int wm = (wid >> 1) * 64, wn = (wid & 1) * 64;
  f32x4 acc[4][4] = {};
  const size_t rowA0 = (size_t)bx * 128;
  const size_t rowB0 = (size_t)by * 128;
  const int sgrp = wid * 2;
  const int r0 = (sgrp * 64 + lane) >> 2;
  const int r1 = ((sgrp + 1) * 64 + lane) >> 2;
  const int cc = ((lane & 3) ^ ((lane >> 3) & 3)) * 8;
  const int lr = lane & 15;
  const int koff = (((lane >> 4) ^ ((lr >> 1) & 3))) * 8;

  for (int k0 = 0; k0 < K; k0 += 32) {
    __syncthreads();
    __builtin_amdgcn_global_load_lds(
        (const AS1 void*)(A + (rowA0 + r0) * K + k0 + cc),
        (AS3 void*)(As + sgrp * 512), 16, 0, 0);
    __builtin_amdgcn_global_load_lds(
        (const AS1 void*)(A + (rowA0 + r1) * K + k0 + cc),
        (AS3 void*)(As + (sgrp + 1) * 512), 16, 0, 0);
    __builtin_amdgcn_global_load_lds(
        (const AS1 void*)(B + (rowB0 + r0) * K + k0 + cc),
        (AS3 void*)(Bs + sgrp * 512), 16, 0, 0);
    __builtin_amdgcn_global_load_lds(
        (const AS1 void*)(B + (rowB0 + r1) * K + k0 + cc),
        (AS3 void*)(Bs + (sgrp + 1) * 512), 16, 0, 0);
    __syncthreads();
    bf16x8 af[4], bf[4];
    #pragma unroll
    for (int m = 0; m < 4; ++m)
      af[m] = *reinterpret_cast<const bf16x8*>(&As[(wm + m * 16 + lr) * 32 + koff]);
    #pragma unroll
    for (int n = 0; n < 4; ++n)
      bf[n] = *reinterpret_cast<const bf16x8*>(&Bs[(wn + n * 16 + lr) * 32 + koff]);
    #pragma unroll
    for (int m = 0; m < 4; ++m)
      #pragma unroll
      for (int n = 0; n < 4; ++n)
        acc[m][n] = __builtin_amdgcn_mfma_f32_16x16x32_bf16(af[m], bf[n], acc[m][n], 0, 0, 0);
  }

  const int rg = (lane >> 4) * 4;
  #pragma unroll
  for (int m = 0; m < 4; ++m) {
    #pragma unroll
    for (int n = 0; n < 4; ++n) {
      const int col = (int)rowB0 + wn + n * 16 + lr;
      #pragma unroll
      for (int r = 0; r < 4; ++r) {
        int row = (int)rowA0 + wm + m * 16 + rg + r;
        float v = acc[m][n][r];
        if (BIAS == 1) v += bias[col];
        if (BIAS == 2) v += bias[row];
        if (OUT8)
          ((unsigned char*)Cv)[(size_t)row * ldc + col] = f2fp8(v);
        else
          ((unsigned short*)Cv)[(size_t)row * ldc + col] = f2bf(v);
      }
    }
  }
}

// Wpv[o,c] = sum_m Wp[o,m] Wvt[c,m]; grid (4,4,1), bf16 out
__global__ __launch_bounds__(256, 2) void gemm_wpv(
    const unsigned short* __restrict__ Wp, const unsigned short* __restrict__ Wvt,
    unsigned short* __restrict__ Wpv) {
  __shared__ unsigned short As[4096], Bs[4096];
  gemm128_body<0, 0>(As, Bs, Wp, Wvt, Wpv, C_DIM, C_DIM, nullptr,
                     blockIdx.x, blockIdx.y);
}

// merged projections: grid (32, 4, 12); sel = z>>2 (0:Q 1:K 2:PVt), bat = z&3
__global__ __launch_bounds__(256, 2) void gemm_proj(
    const unsigned short* __restrict__ Xt,
    const unsigned short* __restrict__ Wq, const unsigned short* __restrict__ Wk,
    const unsigned short* __restrict__ Wpv,
    const float* __restrict__ bq, const float* __restrict__ bk,
    const float* __restrict__ bvp,
    unsigned char* __restrict__ Qb, unsigned char* __restrict__ Kb,
    unsigned char* __restrict__ PVt) {
  __shared__ unsigned short As[4096], Bs[4096];
  const long NCe = (long)N_DIM * C_DIM;
  const long PVe = (long)C_DIM * N_DIM;
  const int sel = blockIdx.z >> 2, bat = blockIdx.z & 3;
  const unsigned short* Xz = Xt + (size_t)bat * NCe;
  if (sel == 0) {
    gemm128_body<1, 1>(As, Bs, Xz, Wq, Qb + (size_t)bat * NCe, C_DIM, C_DIM,
                       bq, blockIdx.x, blockIdx.y);
  } else if (sel == 1) {
    gemm128_body<1, 1>(As, Bs, Xz, Wk, Kb + (size_t)bat * NCe, C_DIM, C_DIM,
                       bk, blockIdx.x, blockIdx.y);
  } else {
    // PVt[o,j] = sum_c Wpv[o,c] Xt[j,c] + bvp[o]; (4,32) tiles via swap
    gemm128_body<2, 1>(As, Bs, Wpv, Xz, PVt + (size_t)bat * PVe, C_DIM, N_DIM,
                       bvp, blockIdx.y, blockIdx.x);
  }
}

// ---------------- MX-fp8 NT GEMM, double-buffered counted-vmcnt -------------
// A,B fp8 e4m3 row-major NT. 256 thr = 4 waves (2x2). M-tile = MFR*32,
// B-tile 128, K-step 128, acc[MFR][4]. mfma_scale_f32_16x16x128_f8f6f4,
// scale=1.0 (e8m0 127) = exact fp8 math at 2x bf16 rate.
// 2 LDS parity buffers; R10-proven loop: BODY(P) reads parity P (staged 2
// tiles ago); BAR (all reads done); STAGE(P, t+2); vmcnt(LOADS) [tile t+1
// landed, t+2 in flight]; BAR. NT even at all call sites.
// __launch_bounds__(256,3): R12-proven no-spill (R13's (256,4) spilled acc).
// Swizzle: phys 16B slot p of row r holds global slot p ^ (r&7); staged via
// pre-swizzled global source (linear gload_lds dest); frag reads land
// directly in i32x8 halves. A-frag: lane l row l&15, k=(l>>4)*32..+31 [R12].
// MODE 0: store fp8 exp(scale*acc); f32 rowsums -> atomicAdd denom[row].
// MODE 1: store f32 acc/denom[col] + bias[row] + resid  (final output).
#define BAR() do { asm volatile("" ::: "memory"); __builtin_amdgcn_s_barrier(); \
                   asm volatile("" ::: "memory"); } while (0)

template<int MFR, int MODE, int GX, int GY>
__global__ __launch_bounds__(256, 3) void gemm_mx(
    const unsigned char* __restrict__ A, long sA,
    const unsigned char* __restrict__ B, long sB,
    void* __restrict__ Cp, long sC,
    int K, int lda, int ldb, int ldc, float scale,
    const float* __restrict__ bias,
    float* __restrict__ denom, long sDen,
    const float* __restrict__ resid, long sR) {
  constexpr int MT   = MFR * 32;         // block M-tile rows
  constexpr int WM   = MFR * 16;         // per-wave M rows
  constexpr int ABUF = MT * 128;         // bytes per A parity buffer
  __shared__ unsigned char Asm[2 * ABUF], Bsm[2 * 16384];

  // XCD-aware bijective block swizzle (nwg % 8 == 0 at all call sites)
  int flat = blockIdx.x + GX * (blockIdx.y + GY * blockIdx.z);
  const int nwg = GX * GY * gridDim.z;
  flat = (flat & 7) * (nwg >> 3) + (flat >> 3);
  const int bx = flat & (GX - 1);
  const int by = (flat / GX) & (GY - 1);
  const int z  = flat / (GX * GY);

  const unsigned char* Ag = A + (size_t)z * sA + (size_t)bx * MT * lda;
  const unsigned char* Bg = B + (size_t)z * sB + (size_t)by * 128 * ldb;
  const int tid = threadIdx.x;
  const int wid = tid >> 6, lane = tid & 63;
  const int wm = (wid >> 1) * WM, wn = (wid & 1) * 64;
  const int lr = lane & 15, q = lane >> 4;
  const int g16 = ((lane & 7) ^ ((lane >> 3) & 7)) * 16;
  const int rl = lr & 7;
  const int rb0 = (((2 * q) ^ rl)) * 16;
  const int rb1 = (((2 * q + 1) ^ rl)) * 16;

  auto STAGE = [&](int P, int tt) {  // P literal at all call sites
    const int k0 = tt << 7;
    #pragma unroll
    for (int i = 0; i < MFR; ++i) {
      const int rr = (i * 4 + wid) * 8 + (lane >> 3);
      __builtin_amdgcn_global_load_lds(
          (const AS1 void*)(Ag + (size_t)rr * lda + k0 + g16),
          (AS3 void*)(Asm + P * ABUF + (i * 4 + wid) * 1024), 16, 0, 0);
    }
    #pragma unroll
    for (int i = 0; i < 4; ++i) {
      const int rr = (i * 4 + wid) * 8 + (lane >> 3);
      __builtin_amdgcn_global_load_lds(
          (const AS1 void*)(Bg + (size_t)rr * ldb + k0 + g16),
          (AS3 void*)(Bsm + P * 16384 + (i * 4 + wid) * 1024), 16, 0, 0);
    }
  };

  f32x4 acc[MFR][4] = {};

  auto BODY = [&](int P) {  // P literal at all call sites
    i32x8 bf[4], af[MFR];
    #pragma unroll
    for (int n = 0; n < 4; ++n) {
      const unsigned char* rp = Bsm + P * 16384 + (wn + n * 16 + lr) * 128;
      *reinterpret_cast<uint4*>(&bf[n]) = *reinterpret_cast<const uint4*>(rp + rb0);
      *(reinterpret_cast<uint4*>(&bf[n]) + 1) = *reinterpret_cast<const uint4*>(rp + rb1);
    }
    #pragma unroll
    for (int mi = 0; mi < MFR; ++mi) {
      const unsigned char* rp = Asm + P * ABUF + (wm + mi * 16 + lr) * 128;
      *reinterpret_cast<uint4*>(&af[mi]) = *reinterpret_cast<const uint4*>(rp + rb0);
      *(reinterpret_cast<uint4*>(&af[mi]) + 1) = *reinterpret_cast<const uint4*>(rp + rb1);
    }
    __builtin_amdgcn_s_setprio(1);
    #pragma unroll
    for (int mi = 0; mi < MFR; ++mi)
      #pragma unroll
      for (int n = 0; n < 4; ++n)
        acc[mi][n] = __builtin_amdgcn_mfma_scale_f32_16x16x128_f8f6f4(
            af[mi], bf[n], acc[mi][n], 0, 0, 0, 127, 0, 127);
    __builtin_amdgcn_s_setprio(0);
  };

  auto WAITV = [&]() {  // one tile (MFR+4 loads) allowed in flight
    if (MFR == 4) asm volatile("s_waitcnt vmcnt(8)" ::: "memory");
    else          asm volatile("s_waitcnt vmcnt(6)" ::: "memory");
  };

  const int NT = K >> 7;  // even at all call sites
  STAGE(0, 0); STAGE(1, 1);
  WAITV();
  BAR();

  for (int t = 0; t < NT; t += 2) {
    BODY(0);
    BAR();
    if (t + 2 < NT) { STAGE(0, t + 2); WAITV(); }
    else { asm volatile("s_waitcnt vmcnt(0)" ::: "memory"); }
    BAR();
    BODY(1);
    if (t + 2 < NT) {
      BAR();
      if (t + 3 < NT) { STAGE(1, t + 3); WAITV(); }
      else { asm volatile("s_waitcnt vmcnt(0)" ::: "memory"); }
      BAR();
    }
  }

  const int rg = q * 4;
  if (MODE == 0) {
    unsigned char* Co = (unsigned char*)Cp + (size_t)z * sC;
    float* Dz = denom + (size_t)z * sDen;
    #pragma unroll
    for (int m = 0; m < MFR; ++m) {
      float ev[4][4];
      #pragma unroll
      for (int n = 0; n < 4; ++n) {
        const int col = by * 128 + wn + n * 16 + lr;
        #pragma unroll
        for (int r = 0; r < 4; ++r) {
          int row = bx * MT + wm + m * 16 + rg + r;
          ev[n][r] = __expf(acc[m][n][r] * scale);
          Co[(size_t)row * ldc + col] = f2fp8(ev[n][r]);
        }
      }
      #pragma unroll
      for (int r = 0; r < 4; ++r) {
        float s = (ev[0][r] + ev[1][r]) + (ev[2][r] + ev[3][r]);
        s += __shfl_xor(s, 1); s += __shfl_xor(s, 2);
        s += __shfl_xor(s, 4); s += __shfl_xor(s, 8);
        if (lr == 0) {
          int row = bx * MT + wm + m * 16 + rg + r;
          atomicAdd(&Dz[row], s);
        }
      }
    }
  } else {
    float* Co = (float*)Cp + (size_t)z * sC;
    const float* Rs = resid + (size_t)z * sR;
    const float* Dz = denom + (size_t)z * sDen;
    #pragma unroll
    for (int n = 0; n < 4; ++n) {
      const int col = by * 128 + wn + n * 16 + lr;
      const float dinv = 1.0f / Dz[col];
      #pragma unroll
      for (int m = 0; m < MFR; ++m)
        #pragma unroll
        for (int r = 0; r < 4; ++r) {
          int row = bx * MT + wm + m * 16 + rg + r;
          size_t idx = (size_t)row * ldc + col;
          Co[idx] = acc[m][n][r] * dinv + bias[row] + Rs[idx];
        }
    }
  }
}

extern "C" void kernel_launch(void* const* d_in, const int* in_sizes, int n_in,
                              void* d_out, int out_size, void* d_ws, size_t ws_size,
                              hipStream_t stream) {
  const float* x  = (const float*)d_in[0];
  const float* wq = (const float*)d_in[1];
  const float* bq = (const float*)d_in[2];
  const float* wk = (const float*)d_in[3];
  const float* bk = (const float*)d_in[4];
  const float* wv = (const float*)d_in[5];
  const float* bv = (const float*)d_in[6];
  const float* wp = (const float*)d_in[7];
  const float* bp = (const float*)d_in[8];
  float* out = (float*)d_out;
  char* ws = (char*)d_ws;
  const size_t MB = 1024 * 1024;
  unsigned short* Wq  = (unsigned short*)(ws + 0);
  unsigned short* Wk  = (unsigned short*)(ws + 512 * 1024);
  unsigned short* Wvt = (unsigned short*)(ws + 1 * MB);
  unsigned short* Wp  = (unsigned short*)(ws + MB + 512 * 1024);
  unsigned short* Wpv = (unsigned short*)(ws + 2 * MB);
  float* bvp = (float*)(ws + 2 * MB + 512 * 1024);        // [512] f32
  unsigned short* Xt  = (unsigned short*)(ws + 3 * MB);   // [B,N,C] bf16
  unsigned char*  Qb8 = (unsigned char*)(ws + 19 * MB);   // [B,N,C] fp8
  unsigned char*  Kb8 = (unsigned char*)(ws + 27 * MB);   // [B,N,C] fp8
  unsigned char*  PVt = (unsigned char*)(ws + 35 * MB);   // [B,C,N] fp8
  float* denom = (float*)(ws + 43 * MB);                  // [B,N] f32
  unsigned char*  P8  = (unsigned char*)(ws + 44 * MB);   // E fp8 [N,N] x (1|4)
  const long NCe = (long)N_DIM * C_DIM;
  const long NNe = (long)N_DIM * N_DIM;
  const long PVe = (long)C_DIM * N_DIM;
  const float rs = 0.044194173824159216f;  // 1/sqrt(512)
  const bool big = ws_size >= 44 * MB + 4 * (size_t)N_DIM * N_DIM;

  cvtT_weights<<<dim3(16, 16, 4), dim3(32, 8), 0, stream>>>(
      wq, wk, wv, wp, Wq, Wk, Wvt, Wp);
  vec_bvp<<<dim3(1), dim3(512), 0, stream>>>(wp, bv, bvp);
  gemm_wpv<<<dim3(4, 4, 1), 256, 0, stream>>>(Wp, Wvt, Wpv);
  transpose_x<<<dim3(N_DIM / 32, C_DIM / 32, B_DIM), dim3(32, 8), 0, stream>>>(x, Xt);
  // Q, K (fp8) and PVt = Wpv.Xt^T + bvp (fp8) in ONE dispatch
  gemm_proj<<<dim3(32, 4, 12), 256, 0, stream>>>(
      Xt, Wq, Wk, Wpv, bq, bk, bvp, Qb8, Kb8, PVt);
  zero_buf<<<dim3(B_DIM * N_DIM / 256), 256, 0, stream>>>(denom, B_DIM * N_DIM);

  if (big) {
    // E = exp(rs * Q.K^T) (fp8); denom[n] += rowsum (f32, pre-rounding)
    gemm_mx<4, 0, 32, 32><<<dim3(32, 32, 4), 256, 0, stream>>>(
        Qb8, NCe, Kb8, NCe, P8, NNe, C_DIM, C_DIM, C_DIM, N_DIM, rs,
        nullptr, denom, N_DIM, nullptr, 0);
    // out[o,n] = (sum_j PVt[o,j] E[n,j]) / denom[n] + bp[o] + x[o,n]
    gemm_mx<2, 1, 8, 32><<<dim3(8, 32, 4), 256, 0, stream>>>(
        PVt, PVe, P8, NNe, out, NCe, N_DIM, N_DIM, N_DIM, N_DIM, 1.0f,
        bp, denom, N_DIM, x, NCe);
  } else {
    for (int b = 0; b < B_DIM; ++b) {
      gemm_mx<4, 0, 32, 32><<<dim3(32, 32, 1), 256, 0, stream>>>(
          Qb8 + (size_t)b * NCe, 0, Kb8 + (size_t)b * NCe, 0, P8, 0,
          C_DIM, C_DIM, C_DIM, N_DIM, rs, nullptr, denom + (size_t)b * N_DIM, 0,
          nullptr, 0);
      gemm_mx<2, 1, 8, 32><<<dim3(8, 32, 1), 256, 0, stream>>>(
          PVt + (size_t)b * PVe, 0, P8, 0, (void*)(out + (size_t)b * NCe), 0,
          N_DIM, N_DIM, N_DIM, N_DIM, 1.0f, bp, denom + (size_t)b * N_DIM, 0,
          x + (size_t)b * NCe, 0);
    }
  }
}

// Round 16
// 207.930 us; speedup vs baseline: 1.3306x; 1.3306x over previous
//
#include <hip/hip_runtime.h>
#include <hip/hip_bf16.h>
#include <stdint.h>

// B=4, C=512, H=W=64 -> N=4096. Channel-first x [B,C,N].
#define C_DIM 512
#define N_DIM 4096
#define B_DIM 4

typedef __bf16 bf16x8 __attribute__((ext_vector_type(8)));
typedef float f32x4 __attribute__((ext_vector_type(4)));
typedef int i32x8 __attribute__((ext_vector_type(8)));
#define AS1 __attribute__((address_space(1)))
#define AS3 __attribute__((address_space(3)))

static __device__ __forceinline__ unsigned short f2bf(float x) {
  unsigned u = __float_as_uint(x);
  unsigned r = (u + 0x7fffu + ((u >> 16) & 1u)) >> 16;
  return (unsigned short)r;
}
static __device__ __forceinline__ unsigned char f2fp8(float x) {
  return (unsigned char)__builtin_amdgcn_cvt_pk_fp8_f32(x, x, 0, false);
}

// weights -> bf16: Wq, Wk, Wp straight; Wv transposed (z==2) for Wpv GEMM.
__global__ __launch_bounds__(256) void cvtT_weights(
    const float* __restrict__ wq, const float* __restrict__ wk,
    const float* __restrict__ wv, const float* __restrict__ wp,
    unsigned short* __restrict__ oq, unsigned short* __restrict__ ok,
    unsigned short* __restrict__ ovt, unsigned short* __restrict__ op) {
  __shared__ float t[32][33];
  const int zz = blockIdx.z;
  const float* w = zz == 0 ? wq : zz == 1 ? wk : zz == 2 ? wv : wp;
  unsigned short* o = zz == 0 ? oq : zz == 1 ? ok : zz == 2 ? ovt : op;
  const int r0 = blockIdx.y * 32, c0 = blockIdx.x * 32;
  const int tx = threadIdx.x, ty = threadIdx.y;
  if (zz == 2) {
    #pragma unroll
    for (int i = ty; i < 32; i += 8) t[i][tx] = w[(r0 + i) * C_DIM + c0 + tx];
    __syncthreads();
    #pragma unroll
    for (int i = ty; i < 32; i += 8)
      o[(size_t)(c0 + i) * C_DIM + r0 + tx] = f2bf(t[tx][i]);
  } else {
    #pragma unroll
    for (int i = ty; i < 32; i += 8)
      o[(size_t)(r0 + i) * C_DIM + c0 + tx] = f2bf(w[(r0 + i) * C_DIM + c0 + tx]);
  }
}

// bvp[o] = sum_m wp[o,m]*bv[m]  (1 block, 512 thr, f32 exact)
__global__ __launch_bounds__(512) void vec_bvp(
    const float* __restrict__ wp, const float* __restrict__ bv,
    float* __restrict__ bvp) {
  const int t = threadIdx.x;
  float s = 0.f;
  #pragma unroll 8
  for (int m = 0; m < C_DIM; ++m) s += wp[(size_t)t * C_DIM + m] * bv[m];
  bvp[t] = s;
}

// x [B,C,N] f32 -> Xt [B,N,C] bf16
__global__ __launch_bounds__(256) void transpose_x(
    const float* __restrict__ x, unsigned short* __restrict__ Xt) {
  __shared__ float t[32][33];
  const int b = blockIdx.z;
  const float* xb = x + (size_t)b * C_DIM * N_DIM;
  unsigned short* xtb = Xt + (size_t)b * N_DIM * C_DIM;
  const int n0 = blockIdx.x * 32, c0 = blockIdx.y * 32;
  const int tx = threadIdx.x, ty = threadIdx.y;
  #pragma unroll
  for (int i = ty; i < 32; i += 8)
    t[i][tx] = xb[(size_t)(c0 + i) * N_DIM + n0 + tx];
  __syncthreads();
  #pragma unroll
  for (int i = ty; i < 32; i += 8)
    xtb[(size_t)(n0 + i) * C_DIM + c0 + tx] = f2bf(t[tx][i]);
}

__global__ __launch_bounds__(256) void zero_buf(float* __restrict__ p, int n) {
  int i = blockIdx.x * 256 + threadIdx.x;
  if (i < n) p[i] = 0.f;
}

// ---------------- 128^2-tile 2-phase NT GEMM body (bf16 inputs) ------------
// BIAS: 0 none, 1 +bias[col], 2 +bias[row]. OUT8: fp8 vs bf16 output.
template<int BIAS, int OUT8>
__device__ __forceinline__ void gemm128_body(
    unsigned short* As, unsigned short* Bs,
    const unsigned short* __restrict__ A, const unsigned short* __restrict__ B,
    void* __restrict__ Cv, int K, int ldc,
    const float* __restrict__ bias, int bx, int by) {
  const int tid = threadIdx.x;
  const int wid = tid >> 6, lane = tid & 63;
  const int wm = (wid >> 1) * 64, wn = (wid & 1) * 64;
  f32x4 acc[4][4] = {};
  const size_t rowA0 = (size_t)bx * 128;
  const size_t rowB0 = (size_t)by * 128;
  const int sgrp = wid * 2;
  const int r0 = (sgrp * 64 + lane) >> 2;
  const int r1 = ((sgrp + 1) * 64 + lane) >> 2;
  const int cc = ((lane & 3) ^ ((lane >> 3) & 3)) * 8;
  const int lr = lane & 15;
  const int koff = (((lane >> 4) ^ ((lr >> 1) & 3))) * 8;

  for (int k0 = 0; k0 < K; k0 += 32) {
    __syncthreads();
    __builtin_amdgcn_global_load_lds(
        (const AS1 void*)(A + (rowA0 + r0) * K + k0 + cc),
        (AS3 void*)(As + sgrp * 512), 16, 0, 0);
    __builtin_amdgcn_global_load_lds(
        (const AS1 void*)(A + (rowA0 + r1) * K + k0 + cc),
        (AS3 void*)(As + (sgrp + 1) * 512), 16, 0, 0);
    __builtin_amdgcn_global_load_lds(
        (const AS1 void*)(B + (rowB0 + r0) * K + k0 + cc),
        (AS3 void*)(Bs + sgrp * 512), 16, 0, 0);
    __builtin_amdgcn_global_load_lds(
        (const AS1 void*)(B + (rowB0 + r1) * K + k0 + cc),
        (AS3 void*)(Bs + (sgrp + 1) * 512), 16, 0, 0);
    __syncthreads();
    bf16x8 af[4], bf[4];
    #pragma unroll
    for (int m = 0; m < 4; ++m)
      af[m] = *reinterpret_cast<const bf16x8*>(&As[(wm + m * 16 + lr) * 32 + koff]);
    #pragma unroll
    for (int n = 0; n < 4; ++n)
      bf[n] = *reinterpret_cast<const bf16x8*>(&Bs[(wn + n * 16 + lr) * 32 + koff]);
    #pragma unroll
    for (int m = 0; m < 4; ++m)
      #pragma unroll
      for (int n = 0; n < 4; ++n)
        acc[m][n] = __builtin_amdgcn_mfma_f32_16x16x32_bf16(af[m], bf[n], acc[m][n], 0, 0, 0);
  }

  const int rg = (lane >> 4) * 4;
  #pragma unroll
  for (int m = 0; m < 4; ++m) {
    #pragma unroll
    for (int n = 0; n < 4; ++n) {
      const int col = (int)rowB0 + wn + n * 16 + lr;
      #pragma unroll
      for (int r = 0; r < 4; ++r) {
        int row = (int)rowA0 + wm + m * 16 + rg + r;
        float v = acc[m][n][r];
        if (BIAS == 1) v += bias[col];
        if (BIAS == 2) v += bias[row];
        if (OUT8)
          ((unsigned char*)Cv)[(size_t)row * ldc + col] = f2fp8(v);
        else
          ((unsigned short*)Cv)[(size_t)row * ldc + col] = f2bf(v);
      }
    }
  }
}

// Wpv[o,c] = sum_m Wp[o,m] Wvt[c,m]; grid (4,4,1), bf16 out
__global__ __launch_bounds__(256, 2) void gemm_wpv(
    const unsigned short* __restrict__ Wp, const unsigned short* __restrict__ Wvt,
    unsigned short* __restrict__ Wpv) {
  __shared__ unsigned short As[4096], Bs[4096];
  gemm128_body<0, 0>(As, Bs, Wp, Wvt, Wpv, C_DIM, C_DIM, nullptr,
                     blockIdx.x, blockIdx.y);
}

// merged projections: grid (32, 4, 12); sel = z>>2 (0:Q 1:K 2:PVt), bat = z&3
__global__ __launch_bounds__(256, 2) void gemm_proj(
    const unsigned short* __restrict__ Xt,
    const unsigned short* __restrict__ Wq, const unsigned short* __restrict__ Wk,
    const unsigned short* __restrict__ Wpv,
    const float* __restrict__ bq, const float* __restrict__ bk,
    const float* __restrict__ bvp,
    unsigned char* __restrict__ Qb, unsigned char* __restrict__ Kb,
    unsigned char* __restrict__ PVt) {
  __shared__ unsigned short As[4096], Bs[4096];
  const long NCe = (long)N_DIM * C_DIM;
  const long PVe = (long)C_DIM * N_DIM;
  const int sel = blockIdx.z >> 2, bat = blockIdx.z & 3;
  const unsigned short* Xz = Xt + (size_t)bat * NCe;
  if (sel == 0) {
    gemm128_body<1, 1>(As, Bs, Xz, Wq, Qb + (size_t)bat * NCe, C_DIM, C_DIM,
                       bq, blockIdx.x, blockIdx.y);
  } else if (sel == 1) {
    gemm128_body<1, 1>(As, Bs, Xz, Wk, Kb + (size_t)bat * NCe, C_DIM, C_DIM,
                       bk, blockIdx.x, blockIdx.y);
  } else {
    // PVt[o,j] = sum_c Wpv[o,c] Xt[j,c] + bvp[o]; (4,32) tiles via swap
    gemm128_body<2, 1>(As, Bs, Wpv, Xz, PVt + (size_t)bat * PVe, C_DIM, N_DIM,
                       bvp, blockIdx.y, blockIdx.x);
  }
}

// ---------------- MX-fp8 NT GEMM (m97 structure, K-step 128) ----------------
// R14-proven best (68.5 us per big GEMM): single-buffered 2-phase, 4 waves,
// __launch_bounds__(256,3) [R13's (256,4) spilled acc -> 577MB scratch;
// R15's double-buffer halved residency (occ 27->11%) and regressed 2x --
// cross-block overlap (m114) at >=2 blocks/CU is the real pipeline; keep
// LDS <= 32KB and VGPR <= ~90].
// A,B fp8 e4m3 row-major NT. M-tile MFR*32, B-tile 128, K-step 128,
// acc[MFR][4]. mfma_scale_f32_16x16x128_f8f6f4, scale=1.0 (e8m0 127).
// Swizzle: phys 16B slot p of row r holds global slot p ^ (r&7); staged via
// pre-swizzled global source (linear gload_lds dest); frag reads land
// directly in i32x8 halves. A-frag: lane l row l&15, k=(l>>4)*32..+31 [R12].
// MODE 0: store fp8 exp(scale*acc); f32 rowsums -> atomicAdd denom[row].
// MODE 1: store f32 acc/denom[col] + bias[row] + resid  (final output).
template<int MFR, int MODE, int GX, int GY>
__global__ __launch_bounds__(256, 3) void gemm_mx(
    const unsigned char* __restrict__ A, long sA,
    const unsigned char* __restrict__ B, long sB,
    void* __restrict__ Cp, long sC,
    int K, int lda, int ldb, int ldc, float scale,
    const float* __restrict__ bias,
    float* __restrict__ denom, long sDen,
    const float* __restrict__ resid, long sR) {
  constexpr int MT = MFR * 32;           // block M-tile rows
  constexpr int WM = MFR * 16;           // per-wave M rows
  __shared__ unsigned char Asm[MT * 128], Bsm[16384];

  // XCD-aware bijective block swizzle (nwg % 8 == 0 at all call sites)
  int flat = blockIdx.x + GX * (blockIdx.y + GY * blockIdx.z);
  const int nwg = GX * GY * gridDim.z;
  flat = (flat & 7) * (nwg >> 3) + (flat >> 3);
  const int bx = flat & (GX - 1);
  const int by = (flat / GX) & (GY - 1);
  const int z  = flat / (GX * GY);

  const unsigned char* Ag = A + (size_t)z * sA + (size_t)bx * MT * lda;
  const unsigned char* Bg = B + (size_t)z * sB + (size_t)by * 128 * ldb;
  const int tid = threadIdx.x;
  const int wid = tid >> 6, lane = tid & 63;
  const int wm = (wid >> 1) * WM, wn = (wid & 1) * 64;
  const int lr = lane & 15, q = lane >> 4;
  const int g16 = ((lane & 7) ^ ((lane >> 3) & 7)) * 16;
  const int rl = lr & 7;
  const int rb0 = (((2 * q) ^ rl)) * 16;
  const int rb1 = (((2 * q + 1) ^ rl)) * 16;

  f32x4 acc[MFR][4] = {};
  const int NT = K >> 7;

  for (int t = 0; t < NT; ++t) {
    __syncthreads();
    const int k0 = t << 7;
    #pragma unroll
    for (int i = 0; i < MFR; ++i) {
      const int rr = (i * 4 + wid) * 8 + (lane >> 3);
      __builtin_amdgcn_global_load_lds(
          (const AS1 void*)(Ag + (size_t)rr * lda + k0 + g16),
          (AS3 void*)(Asm + (i * 4 + wid) * 1024), 16, 0, 0);
    }
    #pragma unroll
    for (int i = 0; i < 4; ++i) {
      const int rr = (i * 4 + wid) * 8 + (lane >> 3);
      __builtin_amdgcn_global_load_lds(
          (const AS1 void*)(Bg + (size_t)rr * ldb + k0 + g16),
          (AS3 void*)(Bsm + (i * 4 + wid) * 1024), 16, 0, 0);
    }
    __syncthreads();  // compiler drains vmcnt(0) before barrier

    i32x8 bf[4], af[MFR];
    #pragma unroll
    for (int n = 0; n < 4; ++n) {
      const unsigned char* rp = Bsm + (wn + n * 16 + lr) * 128;
      *reinterpret_cast<uint4*>(&bf[n]) = *reinterpret_cast<const uint4*>(rp + rb0);
      *(reinterpret_cast<uint4*>(&bf[n]) + 1) = *reinterpret_cast<const uint4*>(rp + rb1);
    }
    #pragma unroll
    for (int mi = 0; mi < MFR; ++mi) {
      const unsigned char* rp = Asm + (wm + mi * 16 + lr) * 128;
      *reinterpret_cast<uint4*>(&af[mi]) = *reinterpret_cast<const uint4*>(rp + rb0);
      *(reinterpret_cast<uint4*>(&af[mi]) + 1) = *reinterpret_cast<const uint4*>(rp + rb1);
    }
    __builtin_amdgcn_s_setprio(1);
    #pragma unroll
    for (int mi = 0; mi < MFR; ++mi)
      #pragma unroll
      for (int n = 0; n < 4; ++n)
        acc[mi][n] = __builtin_amdgcn_mfma_scale_f32_16x16x128_f8f6f4(
            af[mi], bf[n], acc[mi][n], 0, 0, 0, 127, 0, 127);
    __builtin_amdgcn_s_setprio(0);
  }

  const int rg = q * 4;
  if (MODE == 0) {
    unsigned char* Co = (unsigned char*)Cp + (size_t)z * sC;
    float* Dz = denom + (size_t)z * sDen;
    #pragma unroll
    for (int m = 0; m < MFR; ++m) {
      float ev[4][4];
      #pragma unroll
      for (int n = 0; n < 4; ++n) {
        const int col = by * 128 + wn + n * 16 + lr;
        #pragma unroll
        for (int r = 0; r < 4; ++r) {
          int row = bx * MT + wm + m * 16 + rg + r;
          ev[n][r] = __expf(acc[m][n][r] * scale);
          Co[(size_t)row * ldc + col] = f2fp8(ev[n][r]);
        }
      }
      #pragma unroll
      for (int r = 0; r < 4; ++r) {
        float s = (ev[0][r] + ev[1][r]) + (ev[2][r] + ev[3][r]);
        s += __shfl_xor(s, 1); s += __shfl_xor(s, 2);
        s += __shfl_xor(s, 4); s += __shfl_xor(s, 8);
        if (lr == 0) {
          int row = bx * MT + wm + m * 16 + rg + r;
          atomicAdd(&Dz[row], s);
        }
      }
    }
  } else {
    float* Co = (float*)Cp + (size_t)z * sC;
    const float* Rs = resid + (size_t)z * sR;
    const float* Dz = denom + (size_t)z * sDen;
    #pragma unroll
    for (int n = 0; n < 4; ++n) {
      const int col = by * 128 + wn + n * 16 + lr;
      const float dinv = 1.0f / Dz[col];
      #pragma unroll
      for (int m = 0; m < MFR; ++m)
        #pragma unroll
        for (int r = 0; r < 4; ++r) {
          int row = bx * MT + wm + m * 16 + rg + r;
          size_t idx = (size_t)row * ldc + col;
          Co[idx] = acc[m][n][r] * dinv + bias[row] + Rs[idx];
        }
    }
  }
}

extern "C" void kernel_launch(void* const* d_in, const int* in_sizes, int n_in,
                              void* d_out, int out_size, void* d_ws, size_t ws_size,
                              hipStream_t stream) {
  const float* x  = (const float*)d_in[0];
  const float* wq = (const float*)d_in[1];
  const float* bq = (const float*)d_in[2];
  const float* wk = (const float*)d_in[3];
  const float* bk = (const float*)d_in[4];
  const float* wv = (const float*)d_in[5];
  const float* bv = (const float*)d_in[6];
  const float* wp = (const float*)d_in[7];
  const float* bp = (const float*)d_in[8];
  float* out = (float*)d_out;
  char* ws = (char*)d_ws;
  const size_t MB = 1024 * 1024;
  unsigned short* Wq  = (unsigned short*)(ws + 0);
  unsigned short* Wk  = (unsigned short*)(ws + 512 * 1024);
  unsigned short* Wvt = (unsigned short*)(ws + 1 * MB);
  unsigned short* Wp  = (unsigned short*)(ws + MB + 512 * 1024);
  unsigned short* Wpv = (unsigned short*)(ws + 2 * MB);
  float* bvp = (float*)(ws + 2 * MB + 512 * 1024);        // [512] f32
  unsigned short* Xt  = (unsigned short*)(ws + 3 * MB);   // [B,N,C] bf16
  unsigned char*  Qb8 = (unsigned char*)(ws + 19 * MB);   // [B,N,C] fp8
  unsigned char*  Kb8 = (unsigned char*)(ws + 27 * MB);   // [B,N,C] fp8
  unsigned char*  PVt = (unsigned char*)(ws + 35 * MB);   // [B,C,N] fp8
  float* denom = (float*)(ws + 43 * MB);                  // [B,N] f32
  unsigned char*  P8  = (unsigned char*)(ws + 44 * MB);   // E fp8 [N,N] x (1|4)
  const long NCe = (long)N_DIM * C_DIM;
  const long NNe = (long)N_DIM * N_DIM;
  const long PVe = (long)C_DIM * N_DIM;
  const float rs = 0.044194173824159216f;  // 1/sqrt(512)
  const bool big = ws_size >= 44 * MB + 4 * (size_t)N_DIM * N_DIM;

  cvtT_weights<<<dim3(16, 16, 4), dim3(32, 8), 0, stream>>>(
      wq, wk, wv, wp, Wq, Wk, Wvt, Wp);
  vec_bvp<<<dim3(1), dim3(512), 0, stream>>>(wp, bv, bvp);
  gemm_wpv<<<dim3(4, 4, 1), 256, 0, stream>>>(Wp, Wvt, Wpv);
  transpose_x<<<dim3(N_DIM / 32, C_DIM / 32, B_DIM), dim3(32, 8), 0, stream>>>(x, Xt);
  // Q, K (fp8) and PVt = Wpv.Xt^T + bvp (fp8) in ONE dispatch
  gemm_proj<<<dim3(32, 4, 12), 256, 0, stream>>>(
      Xt, Wq, Wk, Wpv, bq, bk, bvp, Qb8, Kb8, PVt);
  zero_buf<<<dim3(B_DIM * N_DIM / 256), 256, 0, stream>>>(denom, B_DIM * N_DIM);

  if (big) {
    // E = exp(rs * Q.K^T) (fp8); denom[n] += rowsum (f32, pre-rounding)
    gemm_mx<4, 0, 32, 32><<<dim3(32, 32, 4), 256, 0, stream>>>(
        Qb8, NCe, Kb8, NCe, P8, NNe, C_DIM, C_DIM, C_DIM, N_DIM, rs,
        nullptr, denom, N_DIM, nullptr, 0);
    // out[o,n] = (sum_j PVt[o,j] E[n,j]) / denom[n] + bp[o] + x[o,n]
    gemm_mx<2, 1, 8, 32><<<dim3(8, 32, 4), 256, 0, stream>>>(
        PVt, PVe, P8, NNe, out, NCe, N_DIM, N_DIM, N_DIM, N_DIM, 1.0f,
        bp, denom, N_DIM, x, NCe);
  } else {
    for (int b = 0; b < B_DIM; ++b) {
      gemm_mx<4, 0, 32, 32><<<dim3(32, 32, 1), 256, 0, stream>>>(
          Qb8 + (size_t)b * NCe, 0, Kb8 + (size_t)b * NCe, 0, P8, 0,
          C_DIM, C_DIM, C_DIM, N_DIM, rs, nullptr, denom + (size_t)b * N_DIM, 0,
          nullptr, 0);
      gemm_mx<2, 1, 8, 32><<<dim3(8, 32, 1), 256, 0, stream>>>(
          PVt + (size_t)b * PVe, 0, P8, 0, (void*)(out + (size_t)b * NCe), 0,
          N_DIM, N_DIM, N_DIM, N_DIM, 1.0f, bp, denom + (size_t)b * N_DIM, 0,
          x + (size_t)b * NCe, 0);
    }
  }
}

// Round 17
// 187.077 us; speedup vs baseline: 1.4789x; 1.1115x over previous
//
#include <hip/hip_runtime.h>
#include <hip/hip_bf16.h>
#include <stdint.h>

// B=4, C=512, H=W=64 -> N=4096. Channel-first x [B,C,N].
#define C_DIM 512
#define N_DIM 4096
#define B_DIM 4

typedef __bf16 bf16x8 __attribute__((ext_vector_type(8)));
typedef float f32x4 __attribute__((ext_vector_type(4)));
typedef int i32x8 __attribute__((ext_vector_type(8)));
#define AS1 __attribute__((address_space(1)))
#define AS3 __attribute__((address_space(3)))

static __device__ __forceinline__ unsigned short f2bf(float x) {
  unsigned u = __float_as_uint(x);
  unsigned r = (u + 0x7fffu + ((u >> 16) & 1u)) >> 16;
  return (unsigned short)r;
}
static __device__ __forceinline__ unsigned char f2fp8(float x) {
  return (unsigned char)__builtin_amdgcn_cvt_pk_fp8_f32(x, x, 0, false);
}

// weights -> bf16 (1024 blocks) + denom zero-fill (blocks >= 1024)
__global__ __launch_bounds__(256) void cvt_weights(
    const float* __restrict__ w0, const float* __restrict__ w1,
    const float* __restrict__ w2, const float* __restrict__ w3,
    unsigned short* __restrict__ o0, unsigned short* __restrict__ o1,
    unsigned short* __restrict__ o2, unsigned short* __restrict__ o3,
    float* __restrict__ denom) {
  int b = blockIdx.x;
  if (b >= 1024) {
    int i = (b - 1024) * 256 + threadIdx.x;
    if (i < B_DIM * N_DIM) denom[i] = 0.f;
    return;
  }
  int i = b * 256 + threadIdx.x;
  o0[i] = f2bf(w0[i]); o1[i] = f2bf(w1[i]);
  o2[i] = f2bf(w2[i]); o3[i] = f2bf(w3[i]);
}

// x [B,C,N] f32 -> Xt [B,N,C] bf16
__global__ __launch_bounds__(256) void transpose_x(
    const float* __restrict__ x, unsigned short* __restrict__ Xt) {
  __shared__ float t[32][33];
  const int b = blockIdx.z;
  const float* xb = x + (size_t)b * C_DIM * N_DIM;
  unsigned short* xtb = Xt + (size_t)b * N_DIM * C_DIM;
  const int n0 = blockIdx.x * 32, c0 = blockIdx.y * 32;
  const int tx = threadIdx.x, ty = threadIdx.y;
  #pragma unroll
  for (int i = ty; i < 32; i += 8)
    t[i][tx] = xb[(size_t)(c0 + i) * N_DIM + n0 + tx];
  __syncthreads();
  #pragma unroll
  for (int i = ty; i < 32; i += 8)
    xtb[(size_t)(n0 + i) * C_DIM + c0 + tx] = f2bf(t[tx][i]);
}

// ---------------- 128^2-tile 2-phase NT GEMM body (bf16 inputs) ------------
// BIAS: 0 none, 1 +bias[col]. OUT8: fp8 vs bf16 output.
template<int BIAS, int OUT8>
__device__ __forceinline__ void gemm128_body(
    unsigned short* As, unsigned short* Bs,
    const unsigned short* __restrict__ A, const unsigned short* __restrict__ B,
    void* __restrict__ Cv, int K, int ldc,
    const float* __restrict__ bias, int bx, int by) {
  const int tid = threadIdx.x;
  const int wid = tid >> 6, lane = tid & 63;
  const int wm = (wid >> 1) * 64, wn = (wid & 1) * 64;
  f32x4 acc[4][4] = {};
  const size_t rowA0 = (size_t)bx * 128;
  const size_t rowB0 = (size_t)by * 128;
  const int sgrp = wid * 2;
  const int r0 = (sgrp * 64 + lane) >> 2;
  const int r1 = ((sgrp + 1) * 64 + lane) >> 2;
  const int cc = ((lane & 3) ^ ((lane >> 3) & 3)) * 8;
  const int lr = lane & 15;
  const int koff = (((lane >> 4) ^ ((lr >> 1) & 3))) * 8;

  for (int k0 = 0; k0 < K; k0 += 32) {
    __syncthreads();
    __builtin_amdgcn_global_load_lds(
        (const AS1 void*)(A + (rowA0 + r0) * K + k0 + cc),
        (AS3 void*)(As + sgrp * 512), 16, 0, 0);
    __builtin_amdgcn_global_load_lds(
        (const AS1 void*)(A + (rowA0 + r1) * K + k0 + cc),
        (AS3 void*)(As + (sgrp + 1) * 512), 16, 0, 0);
    __builtin_amdgcn_global_load_lds(
        (const AS1 void*)(B + (rowB0 + r0) * K + k0 + cc),
        (AS3 void*)(Bs + sgrp * 512), 16, 0, 0);
    __builtin_amdgcn_global_load_lds(
        (const AS1 void*)(B + (rowB0 + r1) * K + k0 + cc),
        (AS3 void*)(Bs + (sgrp + 1) * 512), 16, 0, 0);
    __syncthreads();
    bf16x8 af[4], bf[4];
    #pragma unroll
    for (int m = 0; m < 4; ++m)
      af[m] = *reinterpret_cast<const bf16x8*>(&As[(wm + m * 16 + lr) * 32 + koff]);
    #pragma unroll
    for (int n = 0; n < 4; ++n)
      bf[n] = *reinterpret_cast<const bf16x8*>(&Bs[(wn + n * 16 + lr) * 32 + koff]);
    #pragma unroll
    for (int m = 0; m < 4; ++m)
      #pragma unroll
      for (int n = 0; n < 4; ++n)
        acc[m][n] = __builtin_amdgcn_mfma_f32_16x16x32_bf16(af[m], bf[n], acc[m][n], 0, 0, 0);
  }

  const int rg = (lane >> 4) * 4;
  #pragma unroll
  for (int m = 0; m < 4; ++m) {
    #pragma unroll
    for (int n = 0; n < 4; ++n) {
      const int col = (int)rowB0 + wn + n * 16 + lr;
      #pragma unroll
      for (int r = 0; r < 4; ++r) {
        int row = (int)rowA0 + wm + m * 16 + rg + r;
        float v = acc[m][n][r];
        if (BIAS == 1) v += bias[col];
        if (OUT8)
          ((unsigned char*)Cv)[(size_t)row * ldc + col] = f2fp8(v);
        else
          ((unsigned short*)Cv)[(size_t)row * ldc + col] = f2bf(v);
      }
    }
  }
}

// merged Q,K,V projections: grid (32, 4, 12); z = wsel + 3*batch
// Q,K written as fp8 e4m3; V as bf16 (consumed by gemm_pvt).
__global__ __launch_bounds__(256, 2) void gemm_qkv(
    const unsigned short* __restrict__ Xt,
    const unsigned short* __restrict__ Wq, const unsigned short* __restrict__ Wk,
    const unsigned short* __restrict__ Wv,
    const float* __restrict__ bq, const float* __restrict__ bk,
    const float* __restrict__ bv,
    unsigned char* __restrict__ Qb, unsigned char* __restrict__ Kb,
    unsigned short* __restrict__ Vb) {
  __shared__ unsigned short As[4096], Bs[4096];
  const long NCe = (long)N_DIM * C_DIM;
  const int z = blockIdx.z;
  const int wsel = z % 3, bat = z / 3;
  const unsigned short* Xz = Xt + (size_t)bat * NCe;
  if (wsel == 0) {
    gemm128_body<1, 1>(As, Bs, Xz, Wq, Qb + (size_t)bat * NCe, C_DIM, C_DIM,
                       bq, blockIdx.x, blockIdx.y);
  } else if (wsel == 1) {
    gemm128_body<1, 1>(As, Bs, Xz, Wk, Kb + (size_t)bat * NCe, C_DIM, C_DIM,
                       bk, blockIdx.x, blockIdx.y);
  } else {
    gemm128_body<1, 0>(As, Bs, Xz, Wv, Vb + (size_t)bat * NCe, C_DIM, C_DIM,
                       bv, blockIdx.x, blockIdx.y);
  }
}

// PVt[o,j] = sum_c Wp[o,c] V[j,c] -> fp8; grid (4, 32, 4)
__global__ __launch_bounds__(256, 2) void gemm_pvt(
    const unsigned short* __restrict__ Wp, const unsigned short* __restrict__ Vb,
    unsigned char* __restrict__ PVt) {
  __shared__ unsigned short As[4096], Bs[4096];
  const long NCe = (long)N_DIM * C_DIM;
  const long PVe = (long)C_DIM * N_DIM;
  const int z = blockIdx.z;
  gemm128_body<0, 1>(As, Bs, Wp, Vb + (size_t)z * NCe, PVt + (size_t)z * PVe,
                     C_DIM, N_DIM, nullptr, blockIdx.x, blockIdx.y);
}

// ---------------- MX-fp8 NT GEMM (m97 structure, K-step 128) ----------------
// R12/R14-proven best (68.5 us per big GEMM): single-buffered 2-phase,
// 4 waves (2x2), __launch_bounds__(256,3) [R13's (256,4) spilled acc ->
// 577MB scratch; R15's double-buffer halved residency and regressed 2x —
// cross-block overlap (m114) at >=2 blocks/CU is the real pipeline; keep
// LDS <= 32KB and VGPR <= ~90].
// A,B fp8 e4m3 row-major NT. M-tile MFR*32, B-tile 128, K-step 128,
// acc[MFR][4]. mfma_scale_f32_16x16x128_f8f6f4, scale=1.0 (e8m0 127) =
// exact fp8 math at 2x bf16 rate.
// Swizzle: phys 16B slot p of row r holds global slot p ^ (r&7); staged via
// pre-swizzled global source (linear gload_lds dest); frag reads land
// directly in i32x8 halves. A-frag: lane l row l&15, k=(l>>4)*32..+31 [R12].
// MODE 0: store fp8 exp(scale*acc); f32 rowsums -> atomicAdd denom[row].
// MODE 1: store f32 acc/denom[col] + bias[row] + resid  (final output).
template<int MFR, int MODE, int GX, int GY>
__global__ __launch_bounds__(256, 3) void gemm_mx(
    const unsigned char* __restrict__ A, long sA,
    const unsigned char* __restrict__ B, long sB,
    void* __restrict__ Cp, long sC,
    int K, int lda, int ldb, int ldc, float scale,
    const float* __restrict__ bias,
    float* __restrict__ denom, long sDen,
    const float* __restrict__ resid, long sR) {
  constexpr int MT = MFR * 32;           // block M-tile rows
  constexpr int WM = MFR * 16;           // per-wave M rows
  __shared__ unsigned char Asm[MT * 128], Bsm[16384];

  // XCD-aware bijective block swizzle (nwg % 8 == 0 at all call sites)
  int flat = blockIdx.x + GX * (blockIdx.y + GY * blockIdx.z);
  const int nwg = GX * GY * gridDim.z;
  flat = (flat & 7) * (nwg >> 3) + (flat >> 3);
  const int bx = flat & (GX - 1);
  const int by = (flat / GX) & (GY - 1);
  const int z  = flat / (GX * GY);

  const unsigned char* Ag = A + (size_t)z * sA + (size_t)bx * MT * lda;
  const unsigned char* Bg = B + (size_t)z * sB + (size_t)by * 128 * ldb;
  const int tid = threadIdx.x;
  const int wid = tid >> 6, lane = tid & 63;
  const int wm = (wid >> 1) * WM, wn = (wid & 1) * 64;
  const int lr = lane & 15, q = lane >> 4;
  const int g16 = ((lane & 7) ^ ((lane >> 3) & 7)) * 16;
  const int rl = lr & 7;
  const int rb0 = (((2 * q) ^ rl)) * 16;
  const int rb1 = (((2 * q + 1) ^ rl)) * 16;

  f32x4 acc[MFR][4] = {};
  const int NT = K >> 7;

  for (int t = 0; t < NT; ++t) {
    __syncthreads();
    const int k0 = t << 7;
    #pragma unroll
    for (int i = 0; i < MFR; ++i) {
      const int rr = (i * 4 + wid) * 8 + (lane >> 3);
      __builtin_amdgcn_global_load_lds(
          (const AS1 void*)(Ag + (size_t)rr * lda + k0 + g16),
          (AS3 void*)(Asm + (i * 4 + wid) * 1024), 16, 0, 0);
    }
    #pragma unroll
    for (int i = 0; i < 4; ++i) {
      const int rr = (i * 4 + wid) * 8 + (lane >> 3);
      __builtin_amdgcn_global_load_lds(
          (const AS1 void*)(Bg + (size_t)rr * ldb + k0 + g16),
          (AS3 void*)(Bsm + (i * 4 + wid) * 1024), 16, 0, 0);
    }
    __syncthreads();  // compiler drains vmcnt(0) before barrier

    i32x8 bf[4], af[MFR];
    #pragma unroll
    for (int n = 0; n < 4; ++n) {
      const unsigned char* rp = Bsm + (wn + n * 16 + lr) * 128;
      *reinterpret_cast<uint4*>(&bf[n]) = *reinterpret_cast<const uint4*>(rp + rb0);
      *(reinterpret_cast<uint4*>(&bf[n]) + 1) = *reinterpret_cast<const uint4*>(rp + rb1);
    }
    #pragma unroll
    for (int mi = 0; mi < MFR; ++mi) {
      const unsigned char* rp = Asm + (wm + mi * 16 + lr) * 128;
      *reinterpret_cast<uint4*>(&af[mi]) = *reinterpret_cast<const uint4*>(rp + rb0);
      *(reinterpret_cast<uint4*>(&af[mi]) + 1) = *reinterpret_cast<const uint4*>(rp + rb1);
    }
    __builtin_amdgcn_s_setprio(1);
    #pragma unroll
    for (int mi = 0; mi < MFR; ++mi)
      #pragma unroll
      for (int n = 0; n < 4; ++n)
        acc[mi][n] = __builtin_amdgcn_mfma_scale_f32_16x16x128_f8f6f4(
            af[mi], bf[n], acc[mi][n], 0, 0, 0, 127, 0, 127);
    __builtin_amdgcn_s_setprio(0);
  }

  const int rg = q * 4;
  if (MODE == 0) {
    unsigned char* Co = (unsigned char*)Cp + (size_t)z * sC;
    float* Dz = denom + (size_t)z * sDen;
    #pragma unroll
    for (int m = 0; m < MFR; ++m) {
      float ev[4][4];
      #pragma unroll
      for (int n = 0; n < 4; ++n) {
        const int col = by * 128 + wn + n * 16 + lr;
        #pragma unroll
        for (int r = 0; r < 4; ++r) {
          int row = bx * MT + wm + m * 16 + rg + r;
          ev[n][r] = __expf(acc[m][n][r] * scale);
          Co[(size_t)row * ldc + col] = f2fp8(ev[n][r]);
        }
      }
      #pragma unroll
      for (int r = 0; r < 4; ++r) {
        float s = (ev[0][r] + ev[1][r]) + (ev[2][r] + ev[3][r]);
        s += __shfl_xor(s, 1); s += __shfl_xor(s, 2);
        s += __shfl_xor(s, 4); s += __shfl_xor(s, 8);
        if (lr == 0) {
          int row = bx * MT + wm + m * 16 + rg + r;
          atomicAdd(&Dz[row], s);
        }
      }
    }
  } else {
    float* Co = (float*)Cp + (size_t)z * sC;
    const float* Rs = resid + (size_t)z * sR;
    const float* Dz = denom + (size_t)z * sDen;
    #pragma unroll
    for (int n = 0; n < 4; ++n) {
      const int col = by * 128 + wn + n * 16 + lr;
      const float dinv = 1.0f / Dz[col];
      #pragma unroll
      for (int m = 0; m < MFR; ++m)
        #pragma unroll
        for (int r = 0; r < 4; ++r) {
          int row = bx * MT + wm + m * 16 + rg + r;
          size_t idx = (size_t)row * ldc + col;
          Co[idx] = acc[m][n][r] * dinv + bias[row] + Rs[idx];
        }
    }
  }
}

extern "C" void kernel_launch(void* const* d_in, const int* in_sizes, int n_in,
                              void* d_out, int out_size, void* d_ws, size_t ws_size,
                              hipStream_t stream) {
  const float* x  = (const float*)d_in[0];
  const float* wq = (const float*)d_in[1];
  const float* bq = (const float*)d_in[2];
  const float* wk = (const float*)d_in[3];
  const float* bk = (const float*)d_in[4];
  const float* wv = (const float*)d_in[5];
  const float* bv = (const float*)d_in[6];
  const float* wp = (const float*)d_in[7];
  const float* bp = (const float*)d_in[8];
  float* out = (float*)d_out;
  char* ws = (char*)d_ws;
  const size_t MB = 1024 * 1024;
  unsigned short* Wq  = (unsigned short*)(ws + 0);
  unsigned short* Wk  = (unsigned short*)(ws + 512 * 1024);
  unsigned short* Wv  = (unsigned short*)(ws + 1 * MB);
  unsigned short* Wp  = (unsigned short*)(ws + MB + 512 * 1024);
  unsigned short* Xt  = (unsigned short*)(ws + 2 * MB);   // [B,N,C] bf16
  unsigned char*  Qb8 = (unsigned char*)(ws + 18 * MB);   // [B,N,C] fp8
  unsigned char*  Kb8 = (unsigned char*)(ws + 26 * MB);   // [B,N,C] fp8
  unsigned short* Vb  = (unsigned short*)(ws + 34 * MB);  // [B,N,C] bf16
  unsigned char*  PVt = (unsigned char*)(ws + 50 * MB);   // [B,C,N] fp8
  float* denom = (float*)(ws + 58 * MB);                  // [B,N] f32
  unsigned char*  P8  = (unsigned char*)(ws + 59 * MB);   // E fp8 [N,N] x (1|4)
  const long NCe = (long)N_DIM * C_DIM;
  const long NNe = (long)N_DIM * N_DIM;
  const long PVe = (long)C_DIM * N_DIM;
  const float rs = 0.044194173824159216f;  // 1/sqrt(512)
  const bool big = ws_size >= 59 * MB + 4 * (size_t)N_DIM * N_DIM;

  // weights -> bf16 + denom zero-fill, one dispatch
  cvt_weights<<<dim3(1024 + (B_DIM * N_DIM + 255) / 256), 256, 0, stream>>>(
      wq, wk, wv, wp, Wq, Wk, Wv, Wp, denom);
  transpose_x<<<dim3(N_DIM / 32, C_DIM / 32, B_DIM), dim3(32, 8), 0, stream>>>(x, Xt);
  gemm_qkv<<<dim3(32, 4, 12), 256, 0, stream>>>(
      Xt, Wq, Wk, Wv, bq, bk, bv, Qb8, Kb8, Vb);
  gemm_pvt<<<dim3(4, 32, 4), 256, 0, stream>>>(Wp, Vb, PVt);

  if (big) {
    // E = exp(rs * Q.K^T) (fp8); denom[n] += rowsum (f32, pre-rounding)
    gemm_mx<4, 0, 32, 32><<<dim3(32, 32, 4), 256, 0, stream>>>(
        Qb8, NCe, Kb8, NCe, P8, NNe, C_DIM, C_DIM, C_DIM, N_DIM, rs,
        nullptr, denom, N_DIM, nullptr, 0);
    // out[o,n] = (sum_j PVt[o,j] E[n,j]) / denom[n] + bp[o] + x[o,n]
    gemm_mx<4, 1, 4, 32><<<dim3(4, 32, 4), 256, 0, stream>>>(
        PVt, PVe, P8, NNe, out, NCe, N_DIM, N_DIM, N_DIM, N_DIM, 1.0f,
        bp, denom, N_DIM, x, NCe);
  } else {
    for (int b = 0; b < B_DIM; ++b) {
      gemm_mx<4, 0, 32, 32><<<dim3(32, 32, 1), 256, 0, stream>>>(
          Qb8 + (size_t)b * NCe, 0, Kb8 + (size_t)b * NCe, 0, P8, 0,
          C_DIM, C_DIM, C_DIM, N_DIM, rs, nullptr, denom + (size_t)b * N_DIM, 0,
          nullptr, 0);
      gemm_mx<4, 1, 4, 32><<<dim3(4, 32, 1), 256, 0, stream>>>(
          PVt + (size_t)b * PVe, 0, P8, 0, (void*)(out + (size_t)b * NCe), 0,
          N_DIM, N_DIM, N_DIM, N_DIM, 1.0f, bp, denom + (size_t)b * N_DIM, 0,
          x + (size_t)b * NCe, 0);
    }
  }
}